// Round 2
// baseline (3876.696 us; speedup 1.0000x reference)
//
#include <hip/hip_runtime.h>
#include <cmath>

#define VOCABSZ 50257
#define EMBD 512
#define HIDD 1024
#define CTXD 1024
#define SEQL 50
#define NSTEPS 50
#define BOS_ID 1
#define EOS_ID 2

#define NTHR 256
#define NB_LOGITS 832   // 3328 waves over 50257 rows
#define NB_GATES 1536   // 6144 waves: 3072 gh rows + 3072 gi rows
#define NB_FINAL 64     // 63 logp-writer blocks + 1 attention block

// ws float offsets
#define OFF_M      0        // 50*1024 (M = enc @ Wa)
#define OFF_T      51200    // 64      (t_j = enc_j . ba)
#define OFF_H      51264    // 1024    (current hidden h)
#define OFF_CTX    52288    // 1024    (attention context)
#define OFF_GI     53312    // 3072
#define OFF_GH     56384    // 3072
#define OFF_L      59456    // 50304   (logits)
#define OFF_STATS  109760   // 832*4
#define OFF_STATE  113152   // ints: [0]=emb_idx, [1+s]=done-before-step-s
// total = 113216 floats = 443 KB

__device__ __forceinline__ float wred_sum(float v) {
#pragma unroll
  for (int o = 32; o > 0; o >>= 1) v += __shfl_xor(v, o, 64);
  return v;
}

__device__ __forceinline__ float dot4(float4 a, float4 b) {
  return a.x * b.x + a.y * b.y + a.z * b.z + a.w * b.w;
}

__device__ __forceinline__ float wdot1024(const float* __restrict__ row, int lane,
                                          float4 b0, float4 b1, float4 b2, float4 b3) {
  const float4* r = (const float4*)row;
  float acc = dot4(r[lane], b0) + dot4(r[lane + 64], b1) +
              dot4(r[lane + 128], b2) + dot4(r[lane + 192], b3);
  return wred_sum(acc);
}

// online-softmax + argmax combine; tie -> lower index (matches jnp.argmax)
__device__ __forceinline__ void stat_combine(float& m, float& s, float& v, int& i,
                                             float m2, float s2, float v2, int i2) {
  float mn = fmaxf(m, m2);
  float e1 = (m == -INFINITY) ? 0.f : __expf(m - mn);
  float e2 = (m2 == -INFINITY) ? 0.f : __expf(m2 - mn);
  s = s * e1 + s2 * e2;
  m = mn;
  if (v2 > v || (v2 == v && i2 < i)) { v = v2; i = i2; }
}

// ---------------- K0a: M = enc @ Wa ----------------
__global__ void __launch_bounds__(NTHR)
k0_matM(float* __restrict__ ws, const float* __restrict__ enc,
        const float* __restrict__ Wa) {
  const int blk = blockIdx.x, tid = threadIdx.x;
  const int wave = tid >> 6, lane = tid & 63;
  const int k = blk * 64 + lane;
  float acc[13];
#pragma unroll
  for (int q = 0; q < 13; ++q) acc[q] = 0.f;
  for (int c = 0; c < CTXD; ++c) {
    float w = Wa[(size_t)c * HIDD + k];
#pragma unroll
    for (int q = 0; q < 13; ++q) {
      int j = wave * 13 + q;
      if (j < SEQL) acc[q] += enc[(size_t)j * CTXD + c] * w;
    }
  }
#pragma unroll
  for (int q = 0; q < 13; ++q) {
    int j = wave * 13 + q;
    if (j < SEQL) ws[OFF_M + (size_t)j * HIDD + k] = acc[q];
  }
}

// ---------------- K0b: t = enc@ba, h0 = W_init@hid0+b_init, state init ----------------
__global__ void __launch_bounds__(NTHR)
k0_init(float* __restrict__ ws, const float* __restrict__ enc,
        const float* __restrict__ hid0, const float* __restrict__ Winit,
        const float* __restrict__ binit, const float* __restrict__ ba) {
  const int blk = blockIdx.x, tid = threadIdx.x;
  const int wave = tid >> 6, lane = tid & 63;
  if (blk == 0) {
    const float4* b4 = (const float4*)ba;
    float4 b0 = b4[lane], b1 = b4[lane + 64], b2 = b4[lane + 128], b3 = b4[lane + 192];
    for (int j = wave; j < SEQL; j += 4) {
      float v = wdot1024(enc + (size_t)j * CTXD, lane, b0, b1, b2, b3);
      if (lane == 0) ws[OFF_T + j] = v;
    }
    if (tid == 0) {
      int* st = (int*)(ws + OFF_STATE);
      st[0] = BOS_ID;
      st[1] = 0;
    }
  } else {
    const float4* h4 = (const float4*)hid0;
    float4 b0 = h4[lane], b1 = h4[lane + 64], b2 = h4[lane + 128], b3 = h4[lane + 192];
    int row = (blk - 1) * 4 + wave;  // blocks 1..256 -> rows 0..1023
    float v = wdot1024(Winit + (size_t)row * CTXD, lane, b0, b1, b2, b3) + binit[row];
    if (lane == 0) ws[OFF_H + row] = v;
  }
}

// ---------------- attention (one block): scores, softmax, ctx ----------------
__device__ __forceinline__ void attn_block(float* __restrict__ ws,
                                           const float* __restrict__ enc,
                                           int tid, int wave, int lane,
                                           float* s_h, float* s_sc, float* s_aw) {
  ((float4*)s_h)[tid] = ((const float4*)(ws + OFF_H))[tid];
  __syncthreads();
  const float4* h4 = (const float4*)s_h;
  float4 b0 = h4[lane], b1 = h4[lane + 64], b2 = h4[lane + 128], b3 = h4[lane + 192];
  for (int j = wave; j < SEQL; j += 4) {
    float v = wdot1024(ws + OFF_M + (size_t)j * HIDD, lane, b0, b1, b2, b3) + ws[OFF_T + j];
    if (lane == 0) s_sc[j] = v;
  }
  __syncthreads();
  if (tid < 64) {
    float v = (tid < SEQL) ? s_sc[tid] : -INFINITY;
    float mx = v;
#pragma unroll
    for (int o = 32; o > 0; o >>= 1) mx = fmaxf(mx, __shfl_xor(mx, o, 64));
    float e = (tid < SEQL) ? expf(v - mx) : 0.f;
    float sm = wred_sum(e);
    if (tid < SEQL) s_aw[tid] = e / sm;
  }
  __syncthreads();
  const float4* enc4 = (const float4*)enc;
  float4 acc = make_float4(0.f, 0.f, 0.f, 0.f);
  for (int j = 0; j < SEQL; ++j) {
    float a = s_aw[j];
    float4 ev = enc4[(size_t)j * (CTXD / 4) + tid];
    acc.x += a * ev.x; acc.y += a * ev.y; acc.z += a * ev.z; acc.w += a * ev.w;
  }
  ((float4*)(ws + OFF_CTX))[tid] = acc;
}

__global__ void __launch_bounds__(NTHR)
k_attn0(float* __restrict__ ws, const float* __restrict__ enc) {
  __shared__ float s_h[HIDD];
  __shared__ float s_sc[64], s_aw[64];
  attn_block(ws, enc, threadIdx.x, threadIdx.x >> 6, threadIdx.x & 63, s_h, s_sc, s_aw);
}

// ---------------- gates ----------------
__global__ void __launch_bounds__(NTHR)
k_gates(float* __restrict__ ws, const float* __restrict__ E,
        const float* __restrict__ Wih, const float* __restrict__ Whh,
        const float* __restrict__ bih, const float* __restrict__ bhh) {
  const int tid = threadIdx.x;
  const int wave = tid >> 6, lane = tid & 63;
  const int gw = blockIdx.x * 4 + wave;  // 0..6143
  if (gw < 3 * HIDD) {
    const int r = gw;
    const float4* h4 = (const float4*)(ws + OFF_H);
    float4 b0 = h4[lane], b1 = h4[lane + 64], b2 = h4[lane + 128], b3 = h4[lane + 192];
    float v = wdot1024(Whh + (size_t)r * HIDD, lane, b0, b1, b2, b3) + bhh[r];
    if (lane == 0) ws[OFF_GH + r] = v;
  } else {
    const int r = gw - 3 * HIDD;
    const int emb = ((const int*)(ws + OFF_STATE))[0];
    const float4* e4 = (const float4*)(E + (size_t)emb * EMBD);
    float4 eb0 = e4[lane], eb1 = e4[lane + 64];
    const float4* c4 = (const float4*)(ws + OFF_CTX);
    float4 cb0 = c4[lane], cb1 = c4[lane + 64], cb2 = c4[lane + 128], cb3 = c4[lane + 192];
    const float* rowp = Wih + (size_t)r * (EMBD + CTXD);
    const float4* re = (const float4*)rowp;
    const float4* rc = (const float4*)(rowp + EMBD);
    float acc = dot4(re[lane], eb0) + dot4(re[lane + 64], eb1) +
                dot4(rc[lane], cb0) + dot4(rc[lane + 64], cb1) +
                dot4(rc[lane + 128], cb2) + dot4(rc[lane + 192], cb3);
    float v = wred_sum(acc) + bih[r];
    if (lane == 0) ws[OFF_GI + r] = v;
  }
}

// ---------------- GRU combine (pointwise, h in place, done-masked) ----------------
__global__ void __launch_bounds__(NTHR)
k_gru(float* __restrict__ ws, int s) {
  const int i = blockIdx.x * NTHR + threadIdx.x;  // 0..1023
  const int done = ((const int*)(ws + OFF_STATE))[1 + s];
  float gr = ws[OFF_GI + i];
  float gz = ws[OFF_GI + HIDD + i];
  float gn = ws[OFF_GI + 2 * HIDD + i];
  float hr = ws[OFF_GH + i];
  float hz = ws[OFF_GH + HIDD + i];
  float hn = ws[OFF_GH + 2 * HIDD + i];
  float h = ws[OFF_H + i];
  float r = 1.f / (1.f + expf(-(gr + hr)));
  float z = 1.f / (1.f + expf(-(gz + hz)));
  float n = tanhf(gn + r * hn);
  float hnew = (1.f - z) * n + z * h;
  ws[OFF_H + i] = done ? h : hnew;
}

// ---------------- logits GEMV + per-block softmax/argmax stats ----------------
__global__ void __launch_bounds__(NTHR)
k_logits(float* __restrict__ ws, const float* __restrict__ Wv,
         const float* __restrict__ bv) {
  const int blk = blockIdx.x, tid = threadIdx.x;
  const int wave = tid >> 6, lane = tid & 63;
  __shared__ float s_h[HIDD];
  __shared__ float rm[4], rs[4], rv[4];
  __shared__ int ri[4];
  ((float4*)s_h)[tid] = ((const float4*)(ws + OFF_H))[tid];
  __syncthreads();
  const float4* h4 = (const float4*)s_h;
  float4 b0 = h4[lane], b1 = h4[lane + 64], b2 = h4[lane + 128], b3 = h4[lane + 192];
  float wm = -INFINITY, wsum = 0.f, wv = -INFINITY;
  int wi = 0x7fffffff;
  const int NW = NB_LOGITS * 4;
  for (int row = blk * 4 + wave; row < VOCABSZ; row += NW) {
    float l = wdot1024(Wv + (size_t)row * HIDD, lane, b0, b1, b2, b3) + bv[row];
    if (lane == 0) ws[OFF_L + row] = l;
    float mn = fmaxf(wm, l);
    wsum = ((wm == -INFINITY) ? 0.f : wsum * __expf(wm - mn)) + __expf(l - mn);
    wm = mn;
    if (l > wv || (l == wv && row < wi)) { wv = l; wi = row; }
  }
  if (lane == 0) { rm[wave] = wm; rs[wave] = wsum; rv[wave] = wv; ri[wave] = wi; }
  __syncthreads();
  if (tid == 0) {
    float m = rm[0], ss = rs[0], v = rv[0];
    int ii = ri[0];
#pragma unroll
    for (int w = 1; w < 4; ++w) stat_combine(m, ss, v, ii, rm[w], rs[w], rv[w], ri[w]);
    float* st = ws + OFF_STATS + (size_t)blk * 4;
    st[0] = m; st[1] = ss; st[2] = v; st[3] = __int_as_float(ii);
  }
}

// ---------------- final: combine stats, outputs, state update, next attn ----------------
__global__ void __launch_bounds__(NTHR)
k_final(float* __restrict__ ws, const float* __restrict__ enc,
        float* __restrict__ out, int s) {
  const int blk = blockIdx.x, tid = threadIdx.x;
  __shared__ float s_h[HIDD];
  __shared__ float s_sc[64], s_aw[64];
  __shared__ float rm[NTHR], rs[NTHR], rv[NTHR];
  __shared__ int ri[NTHR];

  if (blk == NB_FINAL - 1) {
    if (s + 1 < NSTEPS)
      attn_block(ws, enc, tid, tid >> 6, tid & 63, s_h, s_sc, s_aw);
    return;
  }

  float m = -INFINITY, ss = 0.f, v = -INFINITY;
  int ii = 0x7fffffff;
  const float4* st4 = (const float4*)(ws + OFF_STATS);
  for (int q = tid; q < NB_LOGITS; q += NTHR) {
    float4 e = st4[q];
    stat_combine(m, ss, v, ii, e.x, e.y, e.z, __float_as_int(e.w));
  }
  rm[tid] = m; rs[tid] = ss; rv[tid] = v; ri[tid] = ii;
  __syncthreads();
  for (int stp = 128; stp > 0; stp >>= 1) {
    if (tid < stp) {
      float ma = rm[tid], sa = rs[tid], va = rv[tid];
      int ia = ri[tid];
      stat_combine(ma, sa, va, ia, rm[tid + stp], rs[tid + stp], rv[tid + stp], ri[tid + stp]);
      rm[tid] = ma; rs[tid] = sa; rv[tid] = va; ri[tid] = ia;
    }
    __syncthreads();
  }
  const float logZ = rm[0] + logf(rs[0]);
  const int gidx = ri[0];

  int* st = (int*)(ws + OFF_STATE);
  const int done = st[1 + s];
  const bool valid = !done;
  const bool is_eos = (gidx == EOS_ID);

  if (blk == 0 && tid == 0) {
    out[s] = (valid && !is_eos) ? (float)gidx : -1.0f;                  // indices
    out[NSTEPS + (size_t)NSTEPS * VOCABSZ + s] = valid ? 1.0f : 0.0f;   // valid
    st[1 + s + 1] = (done || is_eos) ? 1 : 0;
    if (valid && !is_eos) st[0] = gidx;
  }
  float* logp = out + NSTEPS + (size_t)s * VOCABSZ;
  for (int i = blk * NTHR + tid; i < VOCABSZ; i += (NB_FINAL - 1) * NTHR) {
    logp[i] = valid ? (ws[OFF_L + i] - logZ) : 0.f;
  }
}

extern "C" void kernel_launch(void* const* d_in, const int* in_sizes, int n_in,
                              void* d_out, int out_size, void* d_ws, size_t ws_size,
                              hipStream_t stream) {
  const float* enc   = (const float*)d_in[0];
  const float* hid0  = (const float*)d_in[1];
  const float* E     = (const float*)d_in[2];
  const float* Winit = (const float*)d_in[3];
  const float* binit = (const float*)d_in[4];
  const float* Wa    = (const float*)d_in[5];
  const float* ba    = (const float*)d_in[6];
  const float* Wih   = (const float*)d_in[7];
  const float* Whh   = (const float*)d_in[8];
  const float* bih   = (const float*)d_in[9];
  const float* bhh   = (const float*)d_in[10];
  const float* Wv    = (const float*)d_in[11];
  const float* bv    = (const float*)d_in[12];
  float* out = (float*)d_out;
  float* ws  = (float*)d_ws;

  k0_matM<<<16, NTHR, 0, stream>>>(ws, enc, Wa);
  k0_init<<<257, NTHR, 0, stream>>>(ws, enc, hid0, Winit, binit, ba);
  k_attn0<<<1, NTHR, 0, stream>>>(ws, enc);
  for (int s = 0; s < NSTEPS; ++s) {
    k_gates<<<NB_GATES, NTHR, 0, stream>>>(ws, E, Wih, Whh, bih, bhh);
    k_gru<<<4, NTHR, 0, stream>>>(ws, s);
    k_logits<<<NB_LOGITS, NTHR, 0, stream>>>(ws, Wv, bv);
    k_final<<<NB_FINAL, NTHR, 0, stream>>>(ws, enc, out, s);
  }
}

// Round 3
// 2782.819 us; speedup vs baseline: 1.3931x; 1.3931x over previous
//
#include <hip/hip_runtime.h>
#include <cmath>

#define VOCABSZ 50257
#define EMBD 512
#define HIDD 1024
#define CTXD 1024
#define SEQL 50
#define NSTEPS 50
#define BOS_ID 1
#define EOS_ID 2

#define NTHR 256
#define NB_LOGITS 832   // 3328 waves over 50257 rows
#define NB_GATES 1536   // 6144 waves: 3072 gh rows + 3072 gi rows
#define NB_FINAL 64     // 63 logp-writer blocks + 1 attention block

// ws float offsets
#define OFF_M      0        // 50*1024 (M = enc @ Wa)
#define OFF_T      51200    // 64      (t_j = enc_j . ba)
#define OFF_H      51264    // 2*1024  (double-buffered hidden: h_s in buf s&1)
#define OFF_CTX    53312    // 1024    (attention context)
#define OFF_GI     54336    // 3072
#define OFF_GH     57408    // 3072
#define OFF_L      60480    // 50304   (logits)
#define OFF_STATS  110784   // 832*4
#define OFF_STATE  114112   // ints: [0]=emb_idx, [1+s]=done-before-step-s
// total = 114176 floats = 446 KB

__device__ __forceinline__ float wred_sum(float v) {
#pragma unroll
  for (int o = 32; o > 0; o >>= 1) v += __shfl_xor(v, o, 64);
  return v;
}

__device__ __forceinline__ float dot4(float4 a, float4 b) {
  return a.x * b.x + a.y * b.y + a.z * b.z + a.w * b.w;
}

__device__ __forceinline__ float wdot1024(const float* __restrict__ row, int lane,
                                          float4 b0, float4 b1, float4 b2, float4 b3) {
  const float4* r = (const float4*)row;
  float acc = dot4(r[lane], b0) + dot4(r[lane + 64], b1) +
              dot4(r[lane + 128], b2) + dot4(r[lane + 192], b3);
  return wred_sum(acc);
}

// online-softmax + argmax combine; tie -> lower index (matches jnp.argmax)
__device__ __forceinline__ void stat_combine(float& m, float& s, float& v, int& i,
                                             float m2, float s2, float v2, int i2) {
  float mn = fmaxf(m, m2);
  float e1 = (m == -INFINITY) ? 0.f : __expf(m - mn);
  float e2 = (m2 == -INFINITY) ? 0.f : __expf(m2 - mn);
  s = s * e1 + s2 * e2;
  m = mn;
  if (v2 > v || (v2 == v && i2 < i)) { v = v2; i = i2; }
}

// ---------------- K0a: M = enc @ Wa ----------------
// grid (16 kc, 13 jg) x 1024 thr; 16 waves = 4 j's x 4 c-quarters; LDS reduce.
__global__ void __launch_bounds__(1024)
k0_matM(float* __restrict__ ws, const float* __restrict__ enc,
        const float* __restrict__ Wa) {
  const int kc = blockIdx.x;   // 0..15
  const int jg = blockIdx.y;   // 0..12
  const int tid = threadIdx.x;
  const int w = tid >> 6, lane = tid & 63;
  const int jw = w & 3, q = w >> 2;
  const int j = jg * 4 + jw;   // 0..51 (guard < 50)
  const int k = kc * 64 + lane;
  __shared__ float s_red[16][64];
  float acc0 = 0.f, acc1 = 0.f, acc2 = 0.f, acc3 = 0.f;
  if (j < SEQL) {
    const float4* e4 = (const float4*)(enc + (size_t)j * CTXD);
    const float* Wc = Wa + k;
    for (int c4 = q * 64; c4 < q * 64 + 64; ++c4) {
      float4 e = e4[c4];
      const float* wp = Wc + (size_t)(c4 * 4) * HIDD;
      acc0 += e.x * wp[0];
      acc1 += e.y * wp[HIDD];
      acc2 += e.z * wp[2 * HIDD];
      acc3 += e.w * wp[3 * HIDD];
    }
  }
  s_red[w][lane] = acc0 + acc1 + acc2 + acc3;
  __syncthreads();
  if (q == 0 && j < SEQL) {
    float v = s_red[jw][lane] + s_red[4 + jw][lane] +
              s_red[8 + jw][lane] + s_red[12 + jw][lane];
    ws[OFF_M + (size_t)j * HIDD + k] = v;
  }
}

// ---------------- K0b: t = enc@ba, h0 = W_init@hid0+b_init, state init ----------------
__global__ void __launch_bounds__(NTHR)
k0_init(float* __restrict__ ws, const float* __restrict__ enc,
        const float* __restrict__ hid0, const float* __restrict__ Winit,
        const float* __restrict__ binit, const float* __restrict__ ba) {
  const int blk = blockIdx.x, tid = threadIdx.x;
  const int wave = tid >> 6, lane = tid & 63;
  if (blk == 0) {
    const float4* b4 = (const float4*)ba;
    float4 b0 = b4[lane], b1 = b4[lane + 64], b2 = b4[lane + 128], b3 = b4[lane + 192];
    for (int j = wave; j < SEQL; j += 4) {
      float v = wdot1024(enc + (size_t)j * CTXD, lane, b0, b1, b2, b3);
      if (lane == 0) ws[OFF_T + j] = v;
    }
    if (tid == 0) {
      int* st = (int*)(ws + OFF_STATE);
      st[0] = BOS_ID;
      st[1] = 0;
    }
  } else {
    const float4* h4 = (const float4*)hid0;
    float4 b0 = h4[lane], b1 = h4[lane + 64], b2 = h4[lane + 128], b3 = h4[lane + 192];
    int row = (blk - 1) * 4 + wave;  // blocks 1..256 -> rows 0..1023
    float v = wdot1024(Winit + (size_t)row * CTXD, lane, b0, b1, b2, b3) + binit[row];
    if (lane == 0) ws[OFF_H + row] = v;  // h0 -> buf 0
  }
}

// ---------------- attention (one block): scores, softmax, ctx ----------------
__device__ __forceinline__ void attn_block(float* __restrict__ ws, int hoff,
                                           const float* __restrict__ enc,
                                           int tid, int wave, int lane,
                                           float* s_h, float* s_sc, float* s_aw) {
  ((float4*)s_h)[tid] = ((const float4*)(ws + hoff))[tid];
  __syncthreads();
  const float4* h4 = (const float4*)s_h;
  float4 b0 = h4[lane], b1 = h4[lane + 64], b2 = h4[lane + 128], b3 = h4[lane + 192];
  for (int j = wave; j < SEQL; j += 4) {
    float v = wdot1024(ws + OFF_M + (size_t)j * HIDD, lane, b0, b1, b2, b3) + ws[OFF_T + j];
    if (lane == 0) s_sc[j] = v;
  }
  __syncthreads();
  if (tid < 64) {
    float v = (tid < SEQL) ? s_sc[tid] : -INFINITY;
    float mx = v;
#pragma unroll
    for (int o = 32; o > 0; o >>= 1) mx = fmaxf(mx, __shfl_xor(mx, o, 64));
    float e = (tid < SEQL) ? expf(v - mx) : 0.f;
    float sm = wred_sum(e);
    if (tid < SEQL) s_aw[tid] = e / sm;
  }
  __syncthreads();
  const float4* enc4 = (const float4*)enc;
  float4 acc = make_float4(0.f, 0.f, 0.f, 0.f);
  for (int j = 0; j < SEQL; ++j) {
    float a = s_aw[j];
    float4 ev = enc4[(size_t)j * (CTXD / 4) + tid];
    acc.x += a * ev.x; acc.y += a * ev.y; acc.z += a * ev.z; acc.w += a * ev.w;
  }
  ((float4*)(ws + OFF_CTX))[tid] = acc;
}

__global__ void __launch_bounds__(NTHR)
k_attn0(float* __restrict__ ws, const float* __restrict__ enc) {
  __shared__ float s_h[HIDD];
  __shared__ float s_sc[64], s_aw[64];
  attn_block(ws, OFF_H, enc, threadIdx.x, threadIdx.x >> 6, threadIdx.x & 63,
             s_h, s_sc, s_aw);
}

// ---------------- gates: gh = Whh@h_s + bhh ; gi = Wih@[emb;ctx] + bih ----------------
__global__ void __launch_bounds__(NTHR)
k_gates(float* __restrict__ ws, const float* __restrict__ E,
        const float* __restrict__ Wih, const float* __restrict__ Whh,
        const float* __restrict__ bih, const float* __restrict__ bhh, int s) {
  const int tid = threadIdx.x;
  const int wave = tid >> 6, lane = tid & 63;
  const int gw = blockIdx.x * 4 + wave;  // 0..6143
  const int hoff = OFF_H + (s & 1) * HIDD;
  if (gw < 3 * HIDD) {
    const int r = gw;
    const float4* h4 = (const float4*)(ws + hoff);
    float4 b0 = h4[lane], b1 = h4[lane + 64], b2 = h4[lane + 128], b3 = h4[lane + 192];
    float v = wdot1024(Whh + (size_t)r * HIDD, lane, b0, b1, b2, b3) + bhh[r];
    if (lane == 0) ws[OFF_GH + r] = v;
  } else {
    const int r = gw - 3 * HIDD;
    const int emb = ((const int*)(ws + OFF_STATE))[0];
    const float4* e4 = (const float4*)(E + (size_t)emb * EMBD);
    float4 eb0 = e4[lane], eb1 = e4[lane + 64];
    const float4* c4 = (const float4*)(ws + OFF_CTX);
    float4 cb0 = c4[lane], cb1 = c4[lane + 64], cb2 = c4[lane + 128], cb3 = c4[lane + 192];
    const float* rowp = Wih + (size_t)r * (EMBD + CTXD);
    const float4* re = (const float4*)rowp;
    const float4* rc = (const float4*)(rowp + EMBD);
    float acc = dot4(re[lane], eb0) + dot4(re[lane + 64], eb1) +
                dot4(rc[lane], cb0) + dot4(rc[lane + 64], cb1) +
                dot4(rc[lane + 128], cb2) + dot4(rc[lane + 192], cb3);
    float v = wred_sum(acc) + bih[r];
    if (lane == 0) ws[OFF_GI + r] = v;
  }
}

// ---------------- logits: fused GRU -> h_{s+1}; GEMV + per-block stats ----------------
__global__ void __launch_bounds__(NTHR)
k_logits(float* __restrict__ ws, const float* __restrict__ Wv,
         const float* __restrict__ bv, int s) {
  const int blk = blockIdx.x, tid = threadIdx.x;
  const int wave = tid >> 6, lane = tid & 63;
  const int p = s & 1, np = p ^ 1;
  __shared__ float s_h[HIDD];
  __shared__ float rm[4], rs[4], rv[4];
  __shared__ int ri[4];

  // fused pointwise GRU: h_{s+1} from gi/gh/h_s (done-masked), redundantly per block
  const int done = ((const int*)(ws + OFF_STATE))[1 + s];
  const float* hp = ws + OFF_H + p * HIDD;
#pragma unroll
  for (int it = 0; it < HIDD / NTHR; ++it) {
    const int i = tid + it * NTHR;
    float h = hp[i];
    if (done) {
      s_h[i] = h;
    } else {
      float gr = ws[OFF_GI + i];
      float gz = ws[OFF_GI + HIDD + i];
      float gn = ws[OFF_GI + 2 * HIDD + i];
      float r = 1.f / (1.f + __expf(-(gr + ws[OFF_GH + i])));
      float z = 1.f / (1.f + __expf(-(gz + ws[OFF_GH + HIDD + i])));
      float n = tanhf(gn + r * ws[OFF_GH + 2 * HIDD + i]);
      s_h[i] = (1.f - z) * n + z * h;
    }
  }
  __syncthreads();
  if (blk == 0) {  // persist h_{s+1} -> buf np
    ((float4*)(ws + OFF_H + np * HIDD))[tid] = ((const float4*)s_h)[tid];
  }

  const float4* h4 = (const float4*)s_h;
  float4 b0 = h4[lane], b1 = h4[lane + 64], b2 = h4[lane + 128], b3 = h4[lane + 192];
  float wm = -INFINITY, wsum = 0.f, wv = -INFINITY;
  int wi = 0x7fffffff;
  const int NW = NB_LOGITS * 4;
  for (int row = blk * 4 + wave; row < VOCABSZ; row += NW) {
    float l = wdot1024(Wv + (size_t)row * HIDD, lane, b0, b1, b2, b3) + bv[row];
    if (lane == 0) ws[OFF_L + row] = l;
    float mn = fmaxf(wm, l);
    wsum = ((wm == -INFINITY) ? 0.f : wsum * __expf(wm - mn)) + __expf(l - mn);
    wm = mn;
    if (l > wv || (l == wv && row < wi)) { wv = l; wi = row; }
  }
  if (lane == 0) { rm[wave] = wm; rs[wave] = wsum; rv[wave] = wv; ri[wave] = wi; }
  __syncthreads();
  if (tid == 0) {
    float m = rm[0], ss = rs[0], v = rv[0];
    int ii = ri[0];
#pragma unroll
    for (int w = 1; w < 4; ++w) stat_combine(m, ss, v, ii, rm[w], rs[w], rv[w], ri[w]);
    float* st = ws + OFF_STATS + (size_t)blk * 4;
    st[0] = m; st[1] = ss; st[2] = v; st[3] = __int_as_float(ii);
  }
}

// ---------------- final: combine stats, outputs, state update, next attn ----------------
__global__ void __launch_bounds__(NTHR)
k_final(float* __restrict__ ws, const float* __restrict__ enc,
        float* __restrict__ out, int s) {
  const int blk = blockIdx.x, tid = threadIdx.x;
  const int np = (s & 1) ^ 1;
  __shared__ float s_h[HIDD];
  __shared__ float s_sc[64], s_aw[64];
  __shared__ float rm[NTHR], rs[NTHR], rv[NTHR];
  __shared__ int ri[NTHR];

  if (blk == NB_FINAL - 1) {
    if (s + 1 < NSTEPS)  // ctx for step s+1 from h_{s+1}
      attn_block(ws, OFF_H + np * HIDD, enc, tid, tid >> 6, tid & 63, s_h, s_sc, s_aw);
    return;
  }

  float m = -INFINITY, ss = 0.f, v = -INFINITY;
  int ii = 0x7fffffff;
  const float4* st4 = (const float4*)(ws + OFF_STATS);
  for (int q = tid; q < NB_LOGITS; q += NTHR) {
    float4 e = st4[q];
    stat_combine(m, ss, v, ii, e.x, e.y, e.z, __float_as_int(e.w));
  }
  rm[tid] = m; rs[tid] = ss; rv[tid] = v; ri[tid] = ii;
  __syncthreads();
  for (int stp = 128; stp > 0; stp >>= 1) {
    if (tid < stp) {
      float ma = rm[tid], sa = rs[tid], va = rv[tid];
      int ia = ri[tid];
      stat_combine(ma, sa, va, ia, rm[tid + stp], rs[tid + stp], rv[tid + stp], ri[tid + stp]);
      rm[tid] = ma; rs[tid] = sa; rv[tid] = va; ri[tid] = ia;
    }
    __syncthreads();
  }
  const float logZ = rm[0] + logf(rs[0]);
  const int gidx = ri[0];

  int* st = (int*)(ws + OFF_STATE);
  const int done = st[1 + s];
  const bool valid = !done;
  const bool is_eos = (gidx == EOS_ID);

  if (blk == 0 && tid == 0) {
    out[s] = (valid && !is_eos) ? (float)gidx : -1.0f;                  // indices
    out[NSTEPS + (size_t)NSTEPS * VOCABSZ + s] = valid ? 1.0f : 0.0f;   // valid
    st[1 + s + 1] = (done || is_eos) ? 1 : 0;
    if (valid && !is_eos) st[0] = gidx;
  }
  float* logp = out + NSTEPS + (size_t)s * VOCABSZ;
  for (int i = blk * NTHR + tid; i < VOCABSZ; i += (NB_FINAL - 1) * NTHR) {
    logp[i] = valid ? (ws[OFF_L + i] - logZ) : 0.f;
  }
}

extern "C" void kernel_launch(void* const* d_in, const int* in_sizes, int n_in,
                              void* d_out, int out_size, void* d_ws, size_t ws_size,
                              hipStream_t stream) {
  const float* enc   = (const float*)d_in[0];
  const float* hid0  = (const float*)d_in[1];
  const float* E     = (const float*)d_in[2];
  const float* Winit = (const float*)d_in[3];
  const float* binit = (const float*)d_in[4];
  const float* Wa    = (const float*)d_in[5];
  const float* ba    = (const float*)d_in[6];
  const float* Wih   = (const float*)d_in[7];
  const float* Whh   = (const float*)d_in[8];
  const float* bih   = (const float*)d_in[9];
  const float* bhh   = (const float*)d_in[10];
  const float* Wv    = (const float*)d_in[11];
  const float* bv    = (const float*)d_in[12];
  float* out = (float*)d_out;
  float* ws  = (float*)d_ws;

  k0_matM<<<dim3(16, 13), 1024, 0, stream>>>(ws, enc, Wa);
  k0_init<<<257, NTHR, 0, stream>>>(ws, enc, hid0, Winit, binit, ba);
  k_attn0<<<1, NTHR, 0, stream>>>(ws, enc);
  for (int s = 0; s < NSTEPS; ++s) {
    k_gates<<<NB_GATES, NTHR, 0, stream>>>(ws, E, Wih, Whh, bih, bhh, s);
    k_logits<<<NB_LOGITS, NTHR, 0, stream>>>(ws, Wv, bv, s);
    k_final<<<NB_FINAL, NTHR, 0, stream>>>(ws, enc, out, s);
  }
}

// Round 4
// 1840.284 us; speedup vs baseline: 2.1066x; 1.5122x over previous
//
#include <hip/hip_runtime.h>
#include <hip/hip_fp16.h>
#include <cmath>

#define VOCABSZ 50257
#define EMBD 512
#define HIDD 1024
#define CTXD 1024
#define SEQL 50
#define NSTEPS 50
#define BOS_ID 1
#define EOS_ID 2

#define NTHR 256
#define NB_GH 768               // gh blocks (3072 rows, 4 waves each)
#define NB_GI 768               // gi blocks
#define NB_WR 64                // logp writer blocks
#define NB_PRE (NB_GH + NB_GI + NB_WR)   // 1600
#define NB_LOG 832              // logits stats blocks
#define NW_LOG (NB_LOG * 4)     // row stride

// ws float offsets
#define OFF_M      0        // 50*1024 (M = enc @ Wa)
#define OFF_T      51200    // 64      (t_j = enc_j . ba)
#define OFF_H      51264    // 2*1024  (double-buffered hidden: h_s in buf s&1)
#define OFF_CTX    53312    // 1024
#define OFF_GI     54336    // 3072
#define OFF_GH     57408    // 3072
#define OFF_L      60480    // 50304   (logits, padded)
#define OFF_STATS  110784   // 832*8 = 6656 (m,sum,v1,i1,v2,i2,pad,pad)
#define OFF_STATE  117440   // ints: emb[0..50] at +0, done[0..50] at +64 (128 ints)
#define OFF_WVH    117568   // fp16 Wv: 50257*1024 halves = 25731584 floats
// total = 25,849,152 floats = 103.4 MB (ws observed ~800 MB from fill size)

__device__ __forceinline__ float wred_sum(float v) {
#pragma unroll
  for (int o = 32; o > 0; o >>= 1) v += __shfl_xor(v, o, 64);
  return v;
}

__device__ __forceinline__ float dot4(float4 a, float4 b) {
  return a.x * b.x + a.y * b.y + a.z * b.z + a.w * b.w;
}

__device__ __forceinline__ float wdot1024(const float* __restrict__ row, int lane,
                                          float4 b0, float4 b1, float4 b2, float4 b3) {
  const float4* r = (const float4*)row;
  float acc = dot4(r[lane], b0) + dot4(r[lane + 64], b1) +
              dot4(r[lane + 128], b2) + dot4(r[lane + 192], b3);
  return wred_sum(acc);
}

__device__ __forceinline__ bool beats(float v, int i, float v0, int i0) {
  return v > v0 || (v == v0 && i < i0);
}

// merge candidate top-2 (w1,j1,w2,j2) into (v1,i1,v2,i2); tie -> lower index
__device__ __forceinline__ void top2_merge(float& v1, int& i1, float& v2, int& i2,
                                           float w1, int j1, float w2, int j2) {
  if (beats(w1, j1, v1, i1)) {
    float nv2; int ni2;
    if (beats(v1, i1, w2, j2)) { nv2 = v1; ni2 = i1; } else { nv2 = w2; ni2 = j2; }
    v1 = w1; i1 = j1; v2 = nv2; i2 = ni2;
  } else if (beats(w1, j1, v2, i2)) {
    v2 = w1; i2 = j1;
  }
}

// 8 halves (as uint4) dot 8 floats
__device__ __forceinline__ float acc8(uint4 a, const float* b) {
  const __half2* h = reinterpret_cast<const __half2*>(&a);
  float2 f0 = __half22float2(h[0]);
  float2 f1 = __half22float2(h[1]);
  float2 f2 = __half22float2(h[2]);
  float2 f3 = __half22float2(h[3]);
  return f0.x * b[0] + f0.y * b[1] + f1.x * b[2] + f1.y * b[3] +
         f2.x * b[4] + f2.y * b[5] + f3.x * b[6] + f3.y * b[7];
}

// ---------------- f32 -> f16 conversion (Wv) ----------------
__global__ void __launch_bounds__(NTHR)
k_cvt(const float4* __restrict__ src, uint2* __restrict__ dst, int n4) {
  int i = blockIdx.x * NTHR + threadIdx.x;
  const int stride = gridDim.x * NTHR;
  for (; i < n4; i += stride) {
    float4 v = src[i];
    __half2 a = __floats2half2_rn(v.x, v.y);
    __half2 b = __floats2half2_rn(v.z, v.w);
    uint2 u;
    u.x = *reinterpret_cast<unsigned*>(&a);
    u.y = *reinterpret_cast<unsigned*>(&b);
    dst[i] = u;
  }
}

// ---------------- K0a: M = enc @ Wa ----------------
__global__ void __launch_bounds__(1024)
k0_matM(float* __restrict__ ws, const float* __restrict__ enc,
        const float* __restrict__ Wa) {
  const int kc = blockIdx.x;   // 0..15
  const int jg = blockIdx.y;   // 0..12
  const int tid = threadIdx.x;
  const int w = tid >> 6, lane = tid & 63;
  const int jw = w & 3, q = w >> 2;
  const int j = jg * 4 + jw;
  const int k = kc * 64 + lane;
  __shared__ float s_red[16][64];
  float acc0 = 0.f, acc1 = 0.f, acc2 = 0.f, acc3 = 0.f;
  if (j < SEQL) {
    const float4* e4 = (const float4*)(enc + (size_t)j * CTXD);
    const float* Wc = Wa + k;
    for (int c4 = q * 64; c4 < q * 64 + 64; ++c4) {
      float4 e = e4[c4];
      const float* wp = Wc + (size_t)(c4 * 4) * HIDD;
      acc0 += e.x * wp[0];
      acc1 += e.y * wp[HIDD];
      acc2 += e.z * wp[2 * HIDD];
      acc3 += e.w * wp[3 * HIDD];
    }
  }
  s_red[w][lane] = acc0 + acc1 + acc2 + acc3;
  __syncthreads();
  if (q == 0 && j < SEQL) {
    float v = s_red[jw][lane] + s_red[4 + jw][lane] +
              s_red[8 + jw][lane] + s_red[12 + jw][lane];
    ws[OFF_M + (size_t)j * HIDD + k] = v;
  }
}

// ---------------- K0b: t = enc@ba, h0 = W_init@hid0+b_init, state init ----------------
__global__ void __launch_bounds__(NTHR)
k0_init(float* __restrict__ ws, const float* __restrict__ enc,
        const float* __restrict__ hid0, const float* __restrict__ Winit,
        const float* __restrict__ binit, const float* __restrict__ ba) {
  const int blk = blockIdx.x, tid = threadIdx.x;
  const int wave = tid >> 6, lane = tid & 63;
  if (blk == 0) {
    const float4* b4 = (const float4*)ba;
    float4 b0 = b4[lane], b1 = b4[lane + 64], b2 = b4[lane + 128], b3 = b4[lane + 192];
    for (int j = wave; j < SEQL; j += 4) {
      float v = wdot1024(enc + (size_t)j * CTXD, lane, b0, b1, b2, b3);
      if (lane == 0) ws[OFF_T + j] = v;
    }
    if (tid == 0) {
      int* st_emb = (int*)(ws + OFF_STATE);
      st_emb[0] = BOS_ID;    // emb for step 0
      st_emb[64] = 0;        // done[0]
    }
  } else {
    const float4* h4 = (const float4*)hid0;
    float4 b0 = h4[lane], b1 = h4[lane + 64], b2 = h4[lane + 128], b3 = h4[lane + 192];
    int row = (blk - 1) * 4 + wave;
    float v = wdot1024(Winit + (size_t)row * CTXD, lane, b0, b1, b2, b3) + binit[row];
    if (lane == 0) ws[OFF_H + row] = v;  // h0 -> buf 0
  }
}

// ---------------- initial attention (ctx for step 0) ----------------
__global__ void __launch_bounds__(NTHR)
k_attn0(float* __restrict__ ws, const float* __restrict__ enc) {
  const int tid = threadIdx.x;
  const int wave = tid >> 6, lane = tid & 63;
  __shared__ float s_h[HIDD];
  __shared__ float s_sc[64], s_aw[64];
  ((float4*)s_h)[tid] = ((const float4*)(ws + OFF_H))[tid];
  __syncthreads();
  const float4* h4 = (const float4*)s_h;
  float4 b0 = h4[lane], b1 = h4[lane + 64], b2 = h4[lane + 128], b3 = h4[lane + 192];
  for (int j = wave; j < SEQL; j += 4) {
    float v = wdot1024(ws + OFF_M + (size_t)j * HIDD, lane, b0, b1, b2, b3) + ws[OFF_T + j];
    if (lane == 0) s_sc[j] = v;
  }
  __syncthreads();
  if (tid < 64) {
    float v = (tid < SEQL) ? s_sc[tid] : -INFINITY;
    float mx = v;
#pragma unroll
    for (int o = 32; o > 0; o >>= 1) mx = fmaxf(mx, __shfl_xor(mx, o, 64));
    float e = (tid < SEQL) ? expf(v - mx) : 0.f;
    float sm = wred_sum(e);
    if (tid < SEQL) s_aw[tid] = e / sm;
  }
  __syncthreads();
  const float4* enc4 = (const float4*)enc;
  float4 acc = make_float4(0.f, 0.f, 0.f, 0.f);
  for (int j = 0; j < SEQL; ++j) {
    float a = s_aw[j];
    float4 ev = enc4[(size_t)j * (CTXD / 4) + tid];
    acc.x += a * ev.x; acc.y += a * ev.y; acc.z += a * ev.z; acc.w += a * ev.w;
  }
  ((float4*)(ws + OFF_CTX))[tid] = acc;
}

// ---------------- k_pre(s): combine stats of step s-1 -> outputs/state; gates for step s ----------------
__global__ void __launch_bounds__(NTHR)
k_pre(float* __restrict__ ws, const float* __restrict__ E,
      const float* __restrict__ Wih, const float* __restrict__ Whh,
      const float* __restrict__ bih, const float* __restrict__ bhh,
      const float* __restrict__ Wv, const float* __restrict__ bv,
      float* __restrict__ out, int s) {
  const int blk = blockIdx.x, tid = threadIdx.x;
  const int wave = tid >> 6, lane = tid & 63;
  int* st_emb = (int*)(ws + OFF_STATE);
  int* st_done = st_emb + 64;
  const int hoff = OFF_H + (s & 1) * HIDD;

  if (blk < NB_GH) {  // ---- gh rows ----
    if (s >= NSTEPS) return;
    const float4* h4 = (const float4*)(ws + hoff);
    float4 b0 = h4[lane], b1 = h4[lane + 64], b2 = h4[lane + 128], b3 = h4[lane + 192];
    const int r = blk * 4 + wave;
    float v = wdot1024(Whh + (size_t)r * HIDD, lane, b0, b1, b2, b3) + bhh[r];
    if (lane == 0) ws[OFF_GH + r] = v;
    return;
  }

  const bool is_writer = (blk >= NB_GH + NB_GI);
  if (!is_writer && s >= NSTEPS) return;
  if (is_writer && s == 0) return;

  int emb_s = 0, D_s = 0, gidx = -1;
  float logZ = 0.f;
  bool valid = false, eos = false;

  if (s > 0) {
    __shared__ float rm[NTHR], rs_[NTHR], rv1[NTHR], rv2[NTHR];
    __shared__ int ri1[NTHR], ri2[NTHR];
    __shared__ float s_ex[2];
    float m = -INFINITY, su = 0.f, v1 = -INFINITY, v2 = -INFINITY;
    int i1 = 0x7fffffff, i2 = 0x7fffffff;
    const float4* sb = (const float4*)(ws + OFF_STATS);
    for (int q = tid; q < NB_LOG; q += NTHR) {
      float4 A = sb[q * 2];
      float4 B = sb[q * 2 + 1];
      float mn = fmaxf(m, A.x);
      su = ((m == -INFINITY) ? 0.f : su * __expf(m - mn)) + A.y * __expf(A.x - mn);
      m = mn;
      top2_merge(v1, i1, v2, i2, A.z, __float_as_int(A.w), B.x, __float_as_int(B.y));
    }
    rm[tid] = m; rs_[tid] = su; rv1[tid] = v1; ri1[tid] = i1; rv2[tid] = v2; ri2[tid] = i2;
    __syncthreads();
    for (int st = 128; st > 0; st >>= 1) {
      if (tid < st) {
        float m2 = rm[tid + st], s2 = rs_[tid + st];
        float mn = fmaxf(rm[tid], m2);
        rs_[tid] = rs_[tid] * __expf(rm[tid] - mn) + s2 * __expf(m2 - mn);
        rm[tid] = mn;
        float a1 = rv1[tid], a2 = rv2[tid];
        int b1 = ri1[tid], b2 = ri2[tid];
        top2_merge(a1, b1, a2, b2, rv1[tid + st], ri1[tid + st], rv2[tid + st], ri2[tid + st]);
        rv1[tid] = a1; ri1[tid] = b1; rv2[tid] = a2; ri2[tid] = b2;
      }
      __syncthreads();
    }
    const int fi1 = ri1[0], fi2 = ri2[0];
    // exact f32 recompute of the two candidates (removes fp16 argmax risk)
    if (wave < 2) {
      const float4* h4 = (const float4*)(ws + hoff);
      float4 b0 = h4[lane], b1 = h4[lane + 64], b2 = h4[lane + 128], b3 = h4[lane + 192];
      const int r = (wave == 0) ? fi1 : fi2;
      float v = wdot1024(Wv + (size_t)r * HIDD, lane, b0, b1, b2, b3) + bv[r];
      if (lane == 0) s_ex[wave] = v;
    }
    __syncthreads();
    gidx = beats(s_ex[1], fi2, s_ex[0], fi1) ? fi2 : fi1;
    logZ = rm[0] + logf(rs_[0]);
    const int Dp = st_done[s - 1];
    valid = (Dp == 0);
    eos = (gidx == EOS_ID);
    D_s = Dp | (eos ? 1 : 0);
    emb_s = (valid && !eos) ? gidx : st_emb[s - 1];
  } else {
    emb_s = st_emb[0];
  }

  if (!is_writer) {  // ---- gi rows ----
    const int r = (blk - NB_GH) * 4 + wave;
    const float4* e4 = (const float4*)(E + (size_t)emb_s * EMBD);
    float4 eb0 = e4[lane], eb1 = e4[lane + 64];
    const float4* c4 = (const float4*)(ws + OFF_CTX);
    float4 cb0 = c4[lane], cb1 = c4[lane + 64], cb2 = c4[lane + 128], cb3 = c4[lane + 192];
    const float* rowp = Wih + (size_t)r * (EMBD + CTXD);
    const float4* re = (const float4*)rowp;
    const float4* rc = (const float4*)(rowp + EMBD);
    float acc = dot4(re[lane], eb0) + dot4(re[lane + 64], eb1) +
                dot4(rc[lane], cb0) + dot4(rc[lane + 64], cb1) +
                dot4(rc[lane + 128], cb2) + dot4(rc[lane + 192], cb3);
    float v = wred_sum(acc) + bih[r];
    if (lane == 0) ws[OFF_GI + r] = v;
  } else {  // ---- writers: outputs for step s-1 ----
    if (blk == NB_GH + NB_GI && tid == 0) {
      out[s - 1] = (valid && !eos) ? (float)gidx : -1.f;
      out[NSTEPS + (size_t)NSTEPS * VOCABSZ + (s - 1)] = valid ? 1.f : 0.f;
      st_emb[s] = emb_s;
      st_done[s] = D_s;
    }
    float* logp = out + NSTEPS + (size_t)(s - 1) * VOCABSZ;
    for (int i = (blk - (NB_GH + NB_GI)) * NTHR + tid; i < VOCABSZ; i += NB_WR * NTHR)
      logp[i] = valid ? (ws[OFF_L + i] - logZ) : 0.f;
  }
}

// ---------------- k_logits(s): fused GRU -> h_{s+1}; fp16 GEMV + stats; attn for s+1 ----------------
__global__ void __launch_bounds__(NTHR)
k_logits(float* __restrict__ ws, const float* __restrict__ bv,
         const float* __restrict__ enc, int s) {
  const int blk = blockIdx.x, tid = threadIdx.x;
  const int wave = tid >> 6, lane = tid & 63;
  const int p = s & 1, np = p ^ 1;
  __shared__ float s_h[HIDD];
  __shared__ float s_sc[64], s_aw[64];
  __shared__ float sm[4], ssm[4], sv1[4], sv2[4];
  __shared__ int si1[4], si2[4];

  const int* st_emb = (const int*)(ws + OFF_STATE);
  const int done = st_emb[64 + s];  // done[s]

  // fused pointwise GRU (redundant per block)
  const float* hp = ws + OFF_H + p * HIDD;
#pragma unroll
  for (int it = 0; it < HIDD / NTHR; ++it) {
    const int i = tid + it * NTHR;
    float h = hp[i];
    if (done) {
      s_h[i] = h;
    } else {
      float r = 1.f / (1.f + __expf(-(ws[OFF_GI + i] + ws[OFF_GH + i])));
      float z = 1.f / (1.f + __expf(-(ws[OFF_GI + HIDD + i] + ws[OFF_GH + HIDD + i])));
      float n = tanhf(ws[OFF_GI + 2 * HIDD + i] + r * ws[OFF_GH + 2 * HIDD + i]);
      s_h[i] = (1.f - z) * n + z * h;
    }
  }
  __syncthreads();
  if (blk == 0) {  // persist h_{s+1}
    ((float4*)(ws + OFF_H + np * HIDD))[tid] = ((const float4*)s_h)[tid];
  }

  if (blk == NB_LOG) {  // ---- attention for step s+1 ----
    if (s + 1 < NSTEPS) {
      const float4* h4 = (const float4*)s_h;
      float4 b0 = h4[lane], b1 = h4[lane + 64], b2 = h4[lane + 128], b3 = h4[lane + 192];
      for (int j = wave; j < SEQL; j += 4) {
        float v = wdot1024(ws + OFF_M + (size_t)j * HIDD, lane, b0, b1, b2, b3) + ws[OFF_T + j];
        if (lane == 0) s_sc[j] = v;
      }
      __syncthreads();
      if (tid < 64) {
        float v = (tid < SEQL) ? s_sc[tid] : -INFINITY;
        float mx = v;
#pragma unroll
        for (int o = 32; o > 0; o >>= 1) mx = fmaxf(mx, __shfl_xor(mx, o, 64));
        float e = (tid < SEQL) ? expf(v - mx) : 0.f;
        float smv = wred_sum(e);
        if (tid < SEQL) s_aw[tid] = e / smv;
      }
      __syncthreads();
      const float4* enc4 = (const float4*)enc;
      float4 acc = make_float4(0.f, 0.f, 0.f, 0.f);
      for (int j = 0; j < SEQL; ++j) {
        float a = s_aw[j];
        float4 ev = enc4[(size_t)j * (CTXD / 4) + tid];
        acc.x += a * ev.x; acc.y += a * ev.y; acc.z += a * ev.z; acc.w += a * ev.w;
      }
      ((float4*)(ws + OFF_CTX))[tid] = acc;
    }
    return;
  }

  // ---- fp16 logits GEMV + per-wave online stats (m, sum, top-2) ----
  float hb[16];
  {
    const float4* h4 = (const float4*)s_h;
    float4 a = h4[lane * 2], b = h4[lane * 2 + 1];
    float4 c = h4[128 + lane * 2], d = h4[129 + lane * 2];
    hb[0] = a.x; hb[1] = a.y; hb[2] = a.z; hb[3] = a.w;
    hb[4] = b.x; hb[5] = b.y; hb[6] = b.z; hb[7] = b.w;
    hb[8] = c.x; hb[9] = c.y; hb[10] = c.z; hb[11] = c.w;
    hb[12] = d.x; hb[13] = d.y; hb[14] = d.z; hb[15] = d.w;
  }
  const __half* WvH = (const __half*)(ws + OFF_WVH);
  float m = -INFINITY, sum = 0.f, v1 = -INFINITY, v2 = -INFINITY;
  int i1 = 0x7fffffff, i2 = 0x7fffffff;
  for (int row = blk * 4 + wave; row < VOCABSZ; row += NW_LOG) {
    const uint4* r4 = (const uint4*)(WvH + (size_t)row * HIDD);
    float acc = acc8(r4[lane], hb) + acc8(r4[lane + 64], hb + 8);
    float l = wred_sum(acc) + bv[row];
    if (lane == 0) ws[OFF_L + row] = l;
    float mn = fmaxf(m, l);
    sum = ((m == -INFINITY) ? 0.f : sum * __expf(m - mn)) + __expf(l - mn);
    m = mn;
    if (beats(l, row, v1, i1)) { v2 = v1; i2 = i1; v1 = l; i1 = row; }
    else if (beats(l, row, v2, i2)) { v2 = l; i2 = row; }
  }
  if (lane == 0) {
    sm[wave] = m; ssm[wave] = sum;
    sv1[wave] = v1; si1[wave] = i1; sv2[wave] = v2; si2[wave] = i2;
  }
  __syncthreads();
  if (tid == 0) {
    float mm = sm[0], su = ssm[0], a1 = sv1[0], a2 = sv2[0];
    int b1 = si1[0], b2 = si2[0];
#pragma unroll
    for (int w = 1; w < 4; ++w) {
      float mn = fmaxf(mm, sm[w]);
      su = su * __expf(mm - mn) + ssm[w] * __expf(sm[w] - mn);
      mm = mn;
      top2_merge(a1, b1, a2, b2, sv1[w], si1[w], sv2[w], si2[w]);
    }
    float* st = ws + OFF_STATS + (size_t)blk * 8;
    st[0] = mm; st[1] = su;
    st[2] = a1; st[3] = __int_as_float(b1);
    st[4] = a2; st[5] = __int_as_float(b2);
  }
}

extern "C" void kernel_launch(void* const* d_in, const int* in_sizes, int n_in,
                              void* d_out, int out_size, void* d_ws, size_t ws_size,
                              hipStream_t stream) {
  const float* enc   = (const float*)d_in[0];
  const float* hid0  = (const float*)d_in[1];
  const float* E     = (const float*)d_in[2];
  const float* Winit = (const float*)d_in[3];
  const float* binit = (const float*)d_in[4];
  const float* Wa    = (const float*)d_in[5];
  const float* ba    = (const float*)d_in[6];
  const float* Wih   = (const float*)d_in[7];
  const float* Whh   = (const float*)d_in[8];
  const float* bih   = (const float*)d_in[9];
  const float* bhh   = (const float*)d_in[10];
  const float* Wv    = (const float*)d_in[11];
  const float* bv    = (const float*)d_in[12];
  float* out = (float*)d_out;
  float* ws  = (float*)d_ws;

  const int n4 = (VOCABSZ * HIDD) / 4;
  k_cvt<<<4096, NTHR, 0, stream>>>((const float4*)Wv, (uint2*)(ws + OFF_WVH), n4);
  k0_matM<<<dim3(16, 13), 1024, 0, stream>>>(ws, enc, Wa);
  k0_init<<<257, NTHR, 0, stream>>>(ws, enc, hid0, Winit, binit, ba);
  k_attn0<<<1, NTHR, 0, stream>>>(ws, enc);
  for (int s = 0; s < NSTEPS; ++s) {
    k_pre<<<NB_PRE, NTHR, 0, stream>>>(ws, E, Wih, Whh, bih, bhh, Wv, bv, out, s);
    k_logits<<<NB_LOG + 1, NTHR, 0, stream>>>(ws, bv, enc, s);
  }
  k_pre<<<NB_PRE, NTHR, 0, stream>>>(ws, E, Wih, Whh, bih, bhh, Wv, bv, out, NSTEPS);
}